// Round 12
// baseline (559.717 us; speedup 1.0000x reference)
//
#include <hip/hip_runtime.h>
#include <hip/hip_bf16.h>
#include <math.h>

#define NN 50000
#define NE 800000
#define NET (NE + NN)   // edges + self loops
#define FIN 310
#define HD 128
#define NHID 64
#define NCLS 2
#define NG 128
#define NEG_SLOPE 0.2f
#define KP1 320
#define PKB1 (KP1 / 8)              // 40 k-blocks (layer-1 A)
#define PKB2 (HD / 8)               // 16 k-blocks (h/o packed)
#define NT1 (NN / 16)               // 3125 row tiles (NN % 16 == 0)

#define SLOTS 64                    // max degree (Poisson(16)+1; P(>63) ~ 1e-22)
#define NPART 8
#define PART_SZ (NN / NPART)
#define EPB 4096
#define NSLICE ((NET + EPB - 1) / EPB)   // 208
#define NSC (NSLICE * NPART)             // 1664 scatter blocks
#define NWB ((HD * (KP1 + KP2) + 255) / 256)   // castW blocks
#define KP2 128
#define NXB ((NN * PKB1 + 255) / 256)    // castx blocks

#define SELU_SCALE 1.0507009873554804934193349852946f
#define SELU_ALPHA 1.6732632423543772848170429916717f

typedef short bf16x8 __attribute__((ext_vector_type(8)));
typedef float f32x4 __attribute__((ext_vector_type(4)));

__device__ __forceinline__ float selu(float x) {
    return SELU_SCALE * (x > 0.f ? x : SELU_ALPHA * (__expf(x) - 1.f));
}
__device__ __forceinline__ float lrelu(float x) {
    return x > 0.f ? x : NEG_SLOPE * x;
}
__device__ __forceinline__ unsigned short f2bf(float f) {
    unsigned int u = __float_as_uint(f);
    u = (u + 0x7fffu + ((u >> 16) & 1u)) >> 16;
    return (unsigned short)u;
}
__device__ __forceinline__ float bf2f(unsigned short b) {
    return __uint_as_float(((unsigned int)b) << 16);
}

// ---------------- merged pre-processing kernel --------------------------------
// block ranges: [0,NSC) slotted scatter (latency-bound, r8 space-partition);
// [NSC, NSC+NWB) weight cast; [NSC+NWB, ...) x -> Apack fragment-pack.
// The BW-bound cast blocks co-run in the scatter's latency shadow.

__global__ __launch_bounds__(256) void k_pre(const int* __restrict__ ei,
                                             int* __restrict__ cursor,
                                             unsigned short* __restrict__ slots,
                                             const float* __restrict__ W1,
                                             const float* __restrict__ W2,
                                             unsigned short* __restrict__ W1p,
                                             unsigned short* __restrict__ W2p,
                                             const float* __restrict__ x,
                                             unsigned short* __restrict__ Ap) {
    int b = blockIdx.x;
    if (b < NSC) {
        // scatter
        int part = b & (NPART - 1);
        int slice = b >> 3;
        int lo = part * PART_SZ;
        int base = slice * EPB + threadIdx.x;
#pragma unroll
        for (int k = 0; k < EPB / 256; ++k) {
            int i = base + k * 256;
            if (i >= NET) break;
            int d = (i < NE) ? ei[NE + i] : (i - NE);
            if ((unsigned)(d - lo) < (unsigned)PART_SZ) {
                int s = (i < NE) ? ei[i] : d;
                int pos = atomicAdd(&cursor[d], 1) & (SLOTS - 1);
                slots[(size_t)d * SLOTS + pos] = (unsigned short)s;
            }
        }
    } else if (b < NSC + NWB) {
        // weight cast: Wp[kb][n][8]
        int i = (b - NSC) * 256 + threadIdx.x;
        const int N1 = HD * KP1;
        if (i < N1) {
            int n = i / KP1, k = i % KP1;
            unsigned short v = (k < FIN) ? f2bf(W1[(size_t)k * HD + n]) : (unsigned short)0;
            W1p[((k >> 3) * HD + n) * 8 + (k & 7)] = v;
        } else {
            int j = i - N1;
            if (j < HD * KP2) {
                int n = j / KP2, k = j % KP2;
                W2p[((k >> 3) * HD + n) * 8 + (k & 7)] = f2bf(W2[(size_t)k * HD + n]);
            }
        }
    } else {
        // x fragment-pack: Apack[rt][kb][ri][8], zero-padded past FIN
        int i = (b - NSC - NWB) * 256 + threadIdx.x;
        if (i >= NN * PKB1) return;
        int row = i / PKB1, kb = i - row * PKB1;
        int k = kb * 8;
        union { unsigned short u[8]; uint4 q; } af;
        const float* src = x + (size_t)row * FIN + k;
        if (k + 8 <= FIN) {
            float2 f0 = *(const float2*)(src);
            float2 f1 = *(const float2*)(src + 2);
            float2 f2 = *(const float2*)(src + 4);
            float2 f3 = *(const float2*)(src + 6);
            af.u[0] = f2bf(f0.x); af.u[1] = f2bf(f0.y);
            af.u[2] = f2bf(f1.x); af.u[3] = f2bf(f1.y);
            af.u[4] = f2bf(f2.x); af.u[5] = f2bf(f2.y);
            af.u[6] = f2bf(f3.x); af.u[7] = f2bf(f3.y);
        } else {
#pragma unroll
            for (int j = 0; j < 8; ++j)
                af.u[j] = (k + j < FIN) ? f2bf(src[j]) : (unsigned short)0;
        }
        *(uint4*)(Ap + ((((size_t)(row >> 4)) * PKB1 + kb) * 16 + (row & 15)) * 8) = af.q;
    }
}

// ---------------- GEMM epilogue: packed-layout C store + fused dots ----------
// C element (row gr, col c) at [gr>>4][c>>3][gr&15][c&7].

#define PGEMM_EPILOGUE(NTILES)                                                 \
    if (rt < NT1) {                                                            \
        _Pragma("unroll")                                                      \
        for (int r = 0; r < 4; ++r) {                                          \
            int ri = quad * 4 + r;                                             \
            _Pragma("unroll")                                                  \
            for (int nt = 0; nt < NTILES; ++nt) {                              \
                int col = nt * 16 + l16;                                       \
                Cp[((size_t)rt * PKB2 + (col >> 3)) * 128 + ri * 8 + (col & 7)]\
                    = f2bf(acc[nt][r]);                                        \
            }                                                                  \
        }                                                                      \
    }                                                                          \
    _Pragma("unroll")                                                          \
    for (int r = 0; r < 4; ++r) {                                              \
        float s1 = 0.f, s2 = 0.f;                                              \
        _Pragma("unroll")                                                      \
        for (int nt = 0; nt < NTILES; ++nt) {                                  \
            int c = nt * 16 + l16;                                             \
            float v = acc[nt][r];                                              \
            s1 += v * a_src[c];                                                \
            s2 += v * a_dst[c];                                                \
        }                                                                      \
        _Pragma("unroll")                                                      \
        for (int off = 1; off < 16; off <<= 1) {                               \
            s1 += __shfl_xor(s1, off);                                         \
            s2 += __shfl_xor(s2, off);                                         \
        }                                                                      \
        int gr = rt * 16 + quad * 4 + r;                                       \
        if (l16 == 0 && gr < NN) { asrcp[gr] = s1; adstp[gr] = s2; }           \
    }

// ---------------- layer-1 GEMM: packed A (coalesced 1KB loads), B from L2 -----
// no LDS, no barriers; per kstep: 1 A dwordx4 + 8 B loads + 8 MFMA.

__global__ __launch_bounds__(256) void k_gemm1(const unsigned short* __restrict__ Ap,
                                               const unsigned short* __restrict__ Bp,
                                               unsigned short* __restrict__ Cp,
                                               float* __restrict__ asrcp,
                                               float* __restrict__ adstp,
                                               const float* __restrict__ a_src,
                                               const float* __restrict__ a_dst) {
    int t = threadIdx.x;
    int lane = t & 63, w = t >> 6;
    int quad = lane >> 4, l16 = lane & 15;
    int rt = blockIdx.x * 4 + w;
    int rtl = min(rt, NT1 - 1);
    const unsigned short* apack = Ap + (size_t)rtl * PKB1 * 128 + l16 * 8;

    f32x4 acc[8] = {};
#pragma unroll 2
    for (int ks = 0; ks < 10; ++ks) {
        int kb = ks * 4 + quad;
        bf16x8 af = *(const bf16x8*)(apack + (size_t)kb * 128);
        const unsigned short* bb = Bp + (size_t)kb * (HD * 8) + l16 * 8;
#pragma unroll
        for (int nt = 0; nt < 8; ++nt) {
            bf16x8 bfr = *(const bf16x8*)(bb + nt * 128);
            acc[nt] = __builtin_amdgcn_mfma_f32_16x16x32_bf16(af, bfr, acc[nt], 0, 0, 0);
        }
    }
    PGEMM_EPILOGUE(8)
}

// ---------------- layer-2 GEMM: packed A (o from gat), B from L2 -------------

__global__ __launch_bounds__(256) void k_gemm2(const unsigned short* __restrict__ Ap,
                                               const unsigned short* __restrict__ Bp,
                                               unsigned short* __restrict__ Cp,
                                               float* __restrict__ asrcp,
                                               float* __restrict__ adstp,
                                               const float* __restrict__ a_src,
                                               const float* __restrict__ a_dst) {
    int t = threadIdx.x;
    int lane = t & 63, w = t >> 6;
    int quad = lane >> 4, l16 = lane & 15;
    int rt = blockIdx.x * 4 + w;
    int rtl = min(rt, NT1 - 1);
    const unsigned short* apack = Ap + (size_t)rtl * PKB2 * 128 + l16 * 8;

    f32x4 acc[8] = {};
#pragma unroll
    for (int ks = 0; ks < 4; ++ks) {
        int kb = ks * 4 + quad;
        bf16x8 af = *(const bf16x8*)(apack + (size_t)kb * 128);
        const unsigned short* bb = Bp + (size_t)kb * (HD * 8) + l16 * 8;
#pragma unroll
        for (int nt = 0; nt < 8; ++nt) {
            bf16x8 bfr = *(const bf16x8*)(bb + nt * 128);
            acc[nt] = __builtin_amdgcn_mfma_f32_16x16x32_bf16(af, bfr, acc[nt], 0, 0, 0);
        }
    }
    PGEMM_EPILOGUE(8)
}

// ---------------- GAT aggregation (packed h reads, packed o writes) ----------
// chunk for (node s, kb=cl): 16B at [(s>>4)*16+cl][s&15] -- the packed unit IS
// the per-lane gather unit, so packed layout costs nothing here.

__global__ __launch_bounds__(256) void k_gat(const unsigned short* __restrict__ h,
                                             const float* __restrict__ asrc,
                                             const float* __restrict__ adst,
                                             const int* __restrict__ degv,
                                             const unsigned short* __restrict__ slots,
                                             const float* __restrict__ bias,
                                             unsigned short* __restrict__ out) {
    int node = blockIdx.x * 4 + (threadIdx.x >> 6);
    int lane = threadIdx.x & 63;
    if (node >= NN) return;
    int g = lane >> 4, cl = lane & 15;
    int deg = degv[node];
    float adsti = adst[node];

    float2 acc2[4] = {};

    int cnt = min(deg, SLOTS);
    int s_c = 0; float p_c = 0.f;
    if (lane < cnt) {
        s_c = slots[(size_t)node * SLOTS + lane];
        p_c = __expf(lrelu(asrc[s_c] + adsti));
    }
    float den_l = p_c;
    int nt = (cnt + 3) >> 2;   // edge-quads
    for (int t = 0; t < nt; t += 2) {
        float pv[2]; uint4 hv[2];
#pragma unroll
        for (int u = 0; u < 2; ++u) {
            int tt = t + u;
            bool valid = tt < nt;
            int e = (4 * tt + g) & 63;
            int s = __shfl(s_c, e);
            float p = __shfl(p_c, e);
            int sa = valid ? s : 0;
            pv[u] = valid ? p : 0.f;
            hv[u] = *(const uint4*)(h + ((size_t)(sa >> 4) * PKB2 + cl) * 128 + (sa & 15) * 8);
        }
#pragma unroll
        for (int u = 0; u < 2; ++u) {
            float p = pv[u];
            unsigned int w0 = hv[u].x, w1 = hv[u].y, w2 = hv[u].z, w3 = hv[u].w;
            acc2[0].x += p * __uint_as_float(w0 << 16);
            acc2[0].y += p * __uint_as_float(w0 & 0xffff0000u);
            acc2[1].x += p * __uint_as_float(w1 << 16);
            acc2[1].y += p * __uint_as_float(w1 & 0xffff0000u);
            acc2[2].x += p * __uint_as_float(w2 << 16);
            acc2[2].y += p * __uint_as_float(w2 & 0xffff0000u);
            acc2[3].x += p * __uint_as_float(w3 << 16);
            acc2[3].y += p * __uint_as_float(w3 & 0xffff0000u);
        }
    }
#pragma unroll
    for (int k = 0; k < 4; ++k) {
        acc2[k].x += __shfl_xor(acc2[k].x, 16);
        acc2[k].y += __shfl_xor(acc2[k].y, 16);
        acc2[k].x += __shfl_xor(acc2[k].x, 32);
        acc2[k].y += __shfl_xor(acc2[k].y, 32);
    }
#pragma unroll
    for (int off = 32; off; off >>= 1)
        den_l += __shfl_xor(den_l, off);

    if (g == 0) {
        float inv = 1.f / den_l;
        int c0 = cl * 8;
        float4 b0 = *(const float4*)(bias + c0);
        float4 b1 = *(const float4*)(bias + c0 + 4);
        float v0 = selu(acc2[0].x * inv + b0.x);
        float v1 = selu(acc2[0].y * inv + b0.y);
        float v2 = selu(acc2[1].x * inv + b0.z);
        float v3 = selu(acc2[1].y * inv + b0.w);
        float v4 = selu(acc2[2].x * inv + b1.x);
        float v5 = selu(acc2[2].y * inv + b1.y);
        float v6 = selu(acc2[3].x * inv + b1.z);
        float v7 = selu(acc2[3].y * inv + b1.w);
        uint4 pk;
        pk.x = (unsigned int)f2bf(v0) | ((unsigned int)f2bf(v1) << 16);
        pk.y = (unsigned int)f2bf(v2) | ((unsigned int)f2bf(v3) << 16);
        pk.z = (unsigned int)f2bf(v4) | ((unsigned int)f2bf(v5) << 16);
        pk.w = (unsigned int)f2bf(v6) | ((unsigned int)f2bf(v7) << 16);
        *(uint4*)(out + ((size_t)(node >> 4) * PKB2 + cl) * 128 + (node & 15) * 8) = pk;
    }
}

// ---------------- pooling + FC head (packed input) ----------------------------

__device__ __forceinline__ int lower_bound_i(const int* a, int n, int key) {
    int lo = 0, hi = n;
    while (lo < hi) {
        int mid = (lo + hi) >> 1;
        if (a[mid] < key) lo = mid + 1; else hi = mid;
    }
    return lo;
}

__global__ __launch_bounds__(512) void k_poolfc(const unsigned short* __restrict__ x,
                                                const int* __restrict__ batch,
                                                const float* __restrict__ w1,
                                                const float* __restrict__ b1,
                                                const float* __restrict__ w2,
                                                const float* __restrict__ b2,
                                                float* __restrict__ out) {
    int g = blockIdx.x;
    int t = threadIdx.x;
    __shared__ int lo_s, hi_s;
    __shared__ float red[512];
    __shared__ float pooled_s[128];
    if (t == 0) {
        lo_s = lower_bound_i(batch, NN, g);
        hi_s = lower_bound_i(batch, NN, g + 1);
    }
    __syncthreads();
    int lo = lo_s, hi = hi_s;
    int c = t & 127;
    float acc = 0.f;
    for (int n = lo + (t >> 7); n < hi; n += 4)
        acc += bf2f(x[((size_t)(n >> 4) * PKB2 + (c >> 3)) * 128 + (n & 15) * 8 + (c & 7)]);
    red[t] = acc;
    __syncthreads();
    if (t < 128) {
        float v = red[t] + red[t + 128] + red[t + 256] + red[t + 384];
        pooled_s[t] = selu(v / fmaxf((float)(hi - lo), 1.f));
    }
    __syncthreads();
    if (t < 64) {
        float z = 0.f;
#pragma unroll 8
        for (int k = 0; k < HD; ++k) z += pooled_s[k] * w1[k * NHID + t];
        z = selu(z + b1[t]);
        float p0 = z * w2[t * NCLS + 0];
        float p1 = z * w2[t * NCLS + 1];
        for (int off = 32; off; off >>= 1) {
            p0 += __shfl_down(p0, off);
            p1 += __shfl_down(p1, off);
        }
        if (t == 0) {
            float l0 = p0 + b2[0], l1 = p1 + b2[1];
            float m = fmaxf(l0, l1);
            float lse = m + __logf(__expf(l0 - m) + __expf(l1 - m));
            out[g * NCLS + 0] = l0 - lse;
            out[g * NCLS + 1] = l1 - lse;
        }
    }
}

// ---------------- launch ----------------

static inline size_t align_up(size_t v, size_t a) { return (v + a - 1) / a * a; }

extern "C" void kernel_launch(void* const* d_in, const int* in_sizes, int n_in,
                              void* d_out, int out_size, void* d_ws, size_t ws_size,
                              hipStream_t stream) {
    const float* x      = (const float*)d_in[0];
    const int*   ei     = (const int*)d_in[1];
    const int*   batch  = (const int*)d_in[2];
    const float* W1     = (const float*)d_in[3];
    const float* a_src1 = (const float*)d_in[4];
    const float* a_dst1 = (const float*)d_in[5];
    const float* b1     = (const float*)d_in[6];
    const float* W2     = (const float*)d_in[7];
    const float* a_src2 = (const float*)d_in[8];
    const float* a_dst2 = (const float*)d_in[9];
    const float* b2     = (const float*)d_in[10];
    const float* fc1_w  = (const float*)d_in[11];
    const float* fc1_b  = (const float*)d_in[12];
    const float* fc2_w  = (const float*)d_in[13];
    const float* fc2_b  = (const float*)d_in[14];
    float* out = (float*)d_out;

    char* ws = (char*)d_ws;
    size_t off = 0;
    unsigned short* Apack = (unsigned short*)(ws + off); off = align_up(off + (size_t)NN * KP1 * 2, 256);
    unsigned short* h1  = (unsigned short*)(ws + off); off = align_up(off + (size_t)NN * HD * 2 + 256, 256);
    unsigned short* o1  = (unsigned short*)(ws + off); off = align_up(off + (size_t)NN * HD * 2 + 256, 256);
    float* asrc = (float*)(ws + off); off = align_up(off + (size_t)NN * 4, 256);
    float* adst = (float*)(ws + off); off = align_up(off + (size_t)NN * 4, 256);
    int* cursor = (int*)(ws + off);   off = align_up(off + (size_t)NN * 4, 256);
    unsigned short* slots = (unsigned short*)(ws + off); off = align_up(off + (size_t)NN * SLOTS * 2, 256);
    unsigned short* W1p = (unsigned short*)(ws + off); off = align_up(off + (size_t)HD * KP1 * 2, 256);
    unsigned short* W2p = (unsigned short*)(ws + off); off = align_up(off + (size_t)HD * KP2 * 2, 256);
    (void)ws_size;

    // cursor zero, then merged pre-processing (scatter || castW || castx)
    hipMemsetAsync(cursor, 0, (size_t)NN * 4, stream);
    k_pre<<<NSC + NWB + NXB, 256, 0, stream>>>(ei, cursor, slots, W1, W2, W1p, W2p, x, Apack);

    int gblocks = (NT1 + 3) / 4;  // 782

    // Layer 1
    k_gemm1<<<gblocks, 256, 0, stream>>>(Apack, W1p, h1, asrc, adst, a_src1, a_dst1);
    k_gat<<<(NN + 3) / 4, 256, 0, stream>>>(h1, asrc, adst, cursor, slots, b1, o1);

    // Layer 2
    k_gemm2<<<gblocks, 256, 0, stream>>>(o1, W2p, h1, asrc, adst, a_src2, a_dst2);
    k_gat<<<(NN + 3) / 4, 256, 0, stream>>>(h1, asrc, adst, cursor, slots, b2, o1);

    // Pool + FC head
    k_poolfc<<<NG, 512, 0, stream>>>(o1, batch, fc1_w, fc1_b, fc2_w, fc2_b, out);
}

// Round 13
// 293.181 us; speedup vs baseline: 1.9091x; 1.9091x over previous
//
#include <hip/hip_runtime.h>
#include <hip/hip_bf16.h>
#include <math.h>

#define NN 50000
#define NE 800000
#define NET (NE + NN)   // edges + self loops
#define FIN 310
#define HD 128
#define NHID 64
#define NCLS 2
#define NG 128
#define NEG_SLOPE 0.2f
#define KP1 320
#define KP2 128

#define SLOTS 64                    // max degree (Poisson(16)+1; P(>63) ~ 1e-22)
#define NPART 8
#define PART_SZ (NN / NPART)        // 6250
#define EPB 4096
#define NSLICE ((NET + EPB - 1) / EPB)   // 208
#define NSC (NSLICE * NPART)             // 1664 scatter blocks
#define GB1 ((NN + 63) / 64)             // 782 gemm1 blocks

#define SELU_SCALE 1.0507009873554804934193349852946f
#define SELU_ALPHA 1.6732632423543772848170429916717f

typedef short bf16x8 __attribute__((ext_vector_type(8)));
typedef float f32x4 __attribute__((ext_vector_type(4)));

__device__ __forceinline__ float selu(float x) {
    return SELU_SCALE * (x > 0.f ? x : SELU_ALPHA * (__expf(x) - 1.f));
}
__device__ __forceinline__ float lrelu(float x) {
    return x > 0.f ? x : NEG_SLOPE * x;
}
__device__ __forceinline__ unsigned short f2bf(float f) {
    unsigned int u = __float_as_uint(f);
    u = (u + 0x7fffu + ((u >> 16) & 1u)) >> 16;
    return (unsigned short)u;
}
__device__ __forceinline__ float bf2f(unsigned short b) {
    return __uint_as_float(((unsigned int)b) << 16);
}

// ---------------- W cast+transpose (fragment-packed) + cursor zero ------------
// Wp[kb][n][8]: the B-fragment for (kb, quad, l16) is 16B contiguous, and the
// 16 fragments of one n-tile are 16 consecutive 16B chunks -> coalesced.

__global__ void k_castW(const float* __restrict__ W1, const float* __restrict__ W2,
                        unsigned short* __restrict__ W1p, unsigned short* __restrict__ W2p,
                        int* __restrict__ cursor) {
    int i = blockIdx.x * blockDim.x + threadIdx.x;
    if (i < NN) cursor[i] = 0;
    const int N1 = HD * KP1;
    if (i < N1) {
        int n = i / KP1, k = i % KP1;
        unsigned short v = (k < FIN) ? f2bf(W1[(size_t)k * HD + n]) : (unsigned short)0;
        W1p[((k >> 3) * HD + n) * 8 + (k & 7)] = v;
    } else {
        int j = i - N1;
        if (j < HD * KP2) {
            int n = j / KP2, k = j % KP2;
            W2p[((k >> 3) * HD + n) * 8 + (k & 7)] = f2bf(W2[(size_t)k * HD + n]);
        }
    }
}

// ---------------- GEMM epilogue (row-major bf16 C + fused attention dots) -----

#define RGEMM_EPILOGUE                                                         \
    int gr_base = r0 + w * 16 + quad * 4;                                      \
    _Pragma("unroll")                                                          \
    for (int r = 0; r < 4; ++r) {                                              \
        int gr = gr_base + r;                                                  \
        if (gr < M) {                                                          \
            _Pragma("unroll")                                                  \
            for (int nt = 0; nt < 8; ++nt)                                     \
                C[(size_t)gr * HD + nt * 16 + l16] = f2bf(acc[nt][r]);         \
        }                                                                      \
    }                                                                          \
    _Pragma("unroll")                                                          \
    for (int r = 0; r < 4; ++r) {                                              \
        float s1 = 0.f, s2 = 0.f;                                              \
        _Pragma("unroll")                                                      \
        for (int nt = 0; nt < 8; ++nt) {                                       \
            int c = nt * 16 + l16;                                             \
            float v = acc[nt][r];                                              \
            s1 += v * a_src[c];                                                \
            s2 += v * a_dst[c];                                                \
        }                                                                      \
        _Pragma("unroll")                                                      \
        for (int off = 1; off < 16; off <<= 1) {                               \
            s1 += __shfl_xor(s1, off);                                         \
            s2 += __shfl_xor(s2, off);                                         \
        }                                                                      \
        int gr = gr_base + r;                                                  \
        if (l16 == 0 && gr < M) { asrcp[gr] = s1; adstp[gr] = s2; }            \
    }

// ---------------- merged pre: gemm1 blocks [0,GB1) || scatter [GB1,GB1+NSC) ---
// Both are latency-bound at <50% utilization on DIFFERENT resources (MFMA/mem
// vs atomics); co-residency gives ~max instead of sum (47.6 + 42.3 standalone).

__global__ __launch_bounds__(256) void k_pre(const float* __restrict__ A,
                                             const unsigned short* __restrict__ Bp,
                                             unsigned short* __restrict__ C,
                                             float* __restrict__ asrcp,
                                             float* __restrict__ adstp,
                                             const float* __restrict__ a_src,
                                             const float* __restrict__ a_dst,
                                             int M,
                                             const int* __restrict__ ei,
                                             int* __restrict__ cursor,
                                             unsigned short* __restrict__ slots) {
    if (blockIdx.x >= GB1) {
        // ---- slotted scatter (r8 variant: space-partition, plain loads) ----
        int b = blockIdx.x - GB1;
        int part = b & (NPART - 1);
        int slice = b >> 3;
        int lo = part * PART_SZ;
        int base = slice * EPB + threadIdx.x;
#pragma unroll
        for (int k = 0; k < EPB / 256; ++k) {
            int i = base + k * 256;
            if (i >= NET) break;
            int d = (i < NE) ? ei[NE + i] : (i - NE);
            if ((unsigned)(d - lo) < (unsigned)PART_SZ) {
                int s = (i < NE) ? ei[i] : d;
                int pos = atomicAdd(&cursor[d], 1) & (SLOTS - 1);
                slots[(size_t)d * SLOTS + pos] = (unsigned short)s;
            }
        }
        return;
    }
    // ---- layer-1 GEMM: fp32 A direct, barrier-free, all-register ----
    int t = threadIdx.x;
    int lane = t & 63, w = t >> 6;
    int quad = lane >> 4, l16 = lane & 15;
    int r0 = blockIdx.x * 64;

    int grow = r0 + w * 16 + l16;
    int arow = min(grow, M - 1);
    const float* aptr = A + (size_t)arow * FIN + quad * 8;

    f32x4 acc[8] = {};
#pragma unroll 2
    for (int k0 = 0; k0 < 288; k0 += 32) {
        const float* ap = aptr + k0;
        float2 f0 = *(const float2*)(ap + 0);
        float2 f1 = *(const float2*)(ap + 2);
        float2 f2 = *(const float2*)(ap + 4);
        float2 f3 = *(const float2*)(ap + 6);
        union { bf16x8 v; unsigned short u[8]; } af;
        af.u[0] = f2bf(f0.x); af.u[1] = f2bf(f0.y);
        af.u[2] = f2bf(f1.x); af.u[3] = f2bf(f1.y);
        af.u[4] = f2bf(f2.x); af.u[5] = f2bf(f2.y);
        af.u[6] = f2bf(f3.x); af.u[7] = f2bf(f3.y);
        const unsigned short* bbase = Bp + ((size_t)(k0 >> 3) + quad) * (HD * 8) + l16 * 8;
#pragma unroll
        for (int nt = 0; nt < 8; ++nt) {
            bf16x8 bfr = *(const bf16x8*)(bbase + nt * 128);
            acc[nt] = __builtin_amdgcn_mfma_f32_16x16x32_bf16(af.v, bfr, acc[nt], 0, 0, 0);
        }
    }
    {   // tail: k0 = 288, predicated vs FIN
        int kb = 288 + quad * 8;
        union { bf16x8 v; unsigned short u[8]; } af;
#pragma unroll
        for (int j = 0; j < 8; ++j)
            af.u[j] = (kb + j < FIN) ? f2bf(aptr[288 + j]) : (unsigned short)0;
        const unsigned short* bbase = Bp + ((size_t)(288 >> 3) + quad) * (HD * 8) + l16 * 8;
#pragma unroll
        for (int nt = 0; nt < 8; ++nt) {
            bf16x8 bfr = *(const bf16x8*)(bbase + nt * 128);
            acc[nt] = __builtin_amdgcn_mfma_f32_16x16x32_bf16(af.v, bfr, acc[nt], 0, 0, 0);
        }
    }
    RGEMM_EPILOGUE
}

// ---------------- layer-2 GEMM: bf16 A, barrier-free, all-register -----------

__global__ __launch_bounds__(256) void k_gemm2(const unsigned short* __restrict__ A,
                                               const unsigned short* __restrict__ Bp,
                                               unsigned short* __restrict__ C,
                                               float* __restrict__ asrcp,
                                               float* __restrict__ adstp,
                                               const float* __restrict__ a_src,
                                               const float* __restrict__ a_dst,
                                               int M) {
    int t = threadIdx.x;
    int lane = t & 63, w = t >> 6;
    int quad = lane >> 4, l16 = lane & 15;
    int r0 = blockIdx.x * 64;

    int grow = r0 + w * 16 + l16;
    int arow = min(grow, M - 1);
    const unsigned short* aptr = A + (size_t)arow * KP2 + quad * 8;

    f32x4 acc[8] = {};
#pragma unroll
    for (int k0 = 0; k0 < KP2; k0 += 32) {
        bf16x8 af = *(const bf16x8*)(aptr + k0);
        const unsigned short* bbase = Bp + ((size_t)(k0 >> 3) + quad) * (HD * 8) + l16 * 8;
#pragma unroll
        for (int nt = 0; nt < 8; ++nt) {
            bf16x8 bfr = *(const bf16x8*)(bbase + nt * 128);
            acc[nt] = __builtin_amdgcn_mfma_f32_16x16x32_bf16(af, bfr, acc[nt], 0, 0, 0);
        }
    }
    RGEMM_EPILOGUE
}

// ---------------- GAT aggregation (row-major h/o, ushort slots) ---------------
// one wave per node; 4 groups of 16 lanes, uint4 (8 bf16) row loads -> 4 edges
// per instr, x2 unroll. exp/sum(exp) == softmax exactly.

__global__ __launch_bounds__(256) void k_gat(const unsigned short* __restrict__ h,
                                             const float* __restrict__ asrc,
                                             const float* __restrict__ adst,
                                             const int* __restrict__ degv,
                                             const unsigned short* __restrict__ slots,
                                             const float* __restrict__ bias,
                                             unsigned short* __restrict__ out) {
    int node = blockIdx.x * 4 + (threadIdx.x >> 6);
    int lane = threadIdx.x & 63;
    if (node >= NN) return;
    int g = lane >> 4, cl = lane & 15;
    int deg = degv[node];
    float adsti = adst[node];

    float2 acc2[4] = {};

    int cnt = min(deg, SLOTS);
    int s_c = 0; float p_c = 0.f;
    if (lane < cnt) {
        s_c = slots[(size_t)node * SLOTS + lane];
        p_c = __expf(lrelu(asrc[s_c] + adsti));
    }
    float den_l = p_c;
    int nt = (cnt + 3) >> 2;   // edge-quads
    for (int t = 0; t < nt; t += 2) {
        float pv[2]; uint4 hv[2];
#pragma unroll
        for (int u = 0; u < 2; ++u) {
            int tt = t + u;
            bool valid = tt < nt;
            int e = (4 * tt + g) & 63;
            int s = __shfl(s_c, e);
            float p = __shfl(p_c, e);
            int sa = valid ? s : 0;
            pv[u] = valid ? p : 0.f;
            hv[u] = *(const uint4*)(h + (size_t)sa * HD + cl * 8);
        }
#pragma unroll
        for (int u = 0; u < 2; ++u) {
            float p = pv[u];
            unsigned int w0 = hv[u].x, w1 = hv[u].y, w2 = hv[u].z, w3 = hv[u].w;
            acc2[0].x += p * __uint_as_float(w0 << 16);
            acc2[0].y += p * __uint_as_float(w0 & 0xffff0000u);
            acc2[1].x += p * __uint_as_float(w1 << 16);
            acc2[1].y += p * __uint_as_float(w1 & 0xffff0000u);
            acc2[2].x += p * __uint_as_float(w2 << 16);
            acc2[2].y += p * __uint_as_float(w2 & 0xffff0000u);
            acc2[3].x += p * __uint_as_float(w3 << 16);
            acc2[3].y += p * __uint_as_float(w3 & 0xffff0000u);
        }
    }
#pragma unroll
    for (int k = 0; k < 4; ++k) {
        acc2[k].x += __shfl_xor(acc2[k].x, 16);
        acc2[k].y += __shfl_xor(acc2[k].y, 16);
        acc2[k].x += __shfl_xor(acc2[k].x, 32);
        acc2[k].y += __shfl_xor(acc2[k].y, 32);
    }
#pragma unroll
    for (int off = 32; off; off >>= 1)
        den_l += __shfl_xor(den_l, off);

    if (g == 0) {
        float inv = 1.f / den_l;
        int c0 = cl * 8;
        float4 b0 = *(const float4*)(bias + c0);
        float4 b1 = *(const float4*)(bias + c0 + 4);
        float v0 = selu(acc2[0].x * inv + b0.x);
        float v1 = selu(acc2[0].y * inv + b0.y);
        float v2 = selu(acc2[1].x * inv + b0.z);
        float v3 = selu(acc2[1].y * inv + b0.w);
        float v4 = selu(acc2[2].x * inv + b1.x);
        float v5 = selu(acc2[2].y * inv + b1.y);
        float v6 = selu(acc2[3].x * inv + b1.z);
        float v7 = selu(acc2[3].y * inv + b1.w);
        uint4 pk;
        pk.x = (unsigned int)f2bf(v0) | ((unsigned int)f2bf(v1) << 16);
        pk.y = (unsigned int)f2bf(v2) | ((unsigned int)f2bf(v3) << 16);
        pk.z = (unsigned int)f2bf(v4) | ((unsigned int)f2bf(v5) << 16);
        pk.w = (unsigned int)f2bf(v6) | ((unsigned int)f2bf(v7) << 16);
        *(uint4*)(out + (size_t)node * HD + c0) = pk;
    }
}

// ---------------- pooling + FC head (fused, one block per graph) ----------------

__device__ __forceinline__ int lower_bound_i(const int* a, int n, int key) {
    int lo = 0, hi = n;
    while (lo < hi) {
        int mid = (lo + hi) >> 1;
        if (a[mid] < key) lo = mid + 1; else hi = mid;
    }
    return lo;
}

__global__ __launch_bounds__(512) void k_poolfc(const unsigned short* __restrict__ x,
                                                const int* __restrict__ batch,
                                                const float* __restrict__ w1,
                                                const float* __restrict__ b1,
                                                const float* __restrict__ w2,
                                                const float* __restrict__ b2,
                                                float* __restrict__ out) {
    int g = blockIdx.x;
    int t = threadIdx.x;
    __shared__ int lo_s, hi_s;
    __shared__ float red[512];
    __shared__ float pooled_s[128];
    if (t == 0) {
        lo_s = lower_bound_i(batch, NN, g);
        hi_s = lower_bound_i(batch, NN, g + 1);
    }
    __syncthreads();
    int lo = lo_s, hi = hi_s;
    float acc = 0.f;
    for (int n = lo + (t >> 7); n < hi; n += 4)
        acc += bf2f(x[(size_t)n * HD + (t & 127)]);
    red[t] = acc;
    __syncthreads();
    if (t < 128) {
        float v = red[t] + red[t + 128] + red[t + 256] + red[t + 384];
        pooled_s[t] = selu(v / fmaxf((float)(hi - lo), 1.f));
    }
    __syncthreads();
    if (t < 64) {
        float z = 0.f;
#pragma unroll 8
        for (int k = 0; k < HD; ++k) z += pooled_s[k] * w1[k * NHID + t];
        z = selu(z + b1[t]);
        float p0 = z * w2[t * NCLS + 0];
        float p1 = z * w2[t * NCLS + 1];
        for (int off = 32; off; off >>= 1) {
            p0 += __shfl_down(p0, off);
            p1 += __shfl_down(p1, off);
        }
        if (t == 0) {
            float l0 = p0 + b2[0], l1 = p1 + b2[1];
            float m = fmaxf(l0, l1);
            float lse = m + __logf(__expf(l0 - m) + __expf(l1 - m));
            out[g * NCLS + 0] = l0 - lse;
            out[g * NCLS + 1] = l1 - lse;
        }
    }
}

// ---------------- launch ----------------

static inline size_t align_up(size_t v, size_t a) { return (v + a - 1) / a * a; }

extern "C" void kernel_launch(void* const* d_in, const int* in_sizes, int n_in,
                              void* d_out, int out_size, void* d_ws, size_t ws_size,
                              hipStream_t stream) {
    const float* x      = (const float*)d_in[0];
    const int*   ei     = (const int*)d_in[1];
    const int*   batch  = (const int*)d_in[2];
    const float* W1     = (const float*)d_in[3];
    const float* a_src1 = (const float*)d_in[4];
    const float* a_dst1 = (const float*)d_in[5];
    const float* b1     = (const float*)d_in[6];
    const float* W2     = (const float*)d_in[7];
    const float* a_src2 = (const float*)d_in[8];
    const float* a_dst2 = (const float*)d_in[9];
    const float* b2     = (const float*)d_in[10];
    const float* fc1_w  = (const float*)d_in[11];
    const float* fc1_b  = (const float*)d_in[12];
    const float* fc2_w  = (const float*)d_in[13];
    const float* fc2_b  = (const float*)d_in[14];
    float* out = (float*)d_out;

    char* ws = (char*)d_ws;
    size_t off = 0;
    unsigned short* h1  = (unsigned short*)(ws + off); off = align_up(off + (size_t)NN * HD * 2, 256);
    unsigned short* o1  = (unsigned short*)(ws + off); off = align_up(off + (size_t)NN * HD * 2, 256);
    float* asrc = (float*)(ws + off); off = align_up(off + (size_t)NN * 4, 256);
    float* adst = (float*)(ws + off); off = align_up(off + (size_t)NN * 4, 256);
    int* cursor = (int*)(ws + off);   off = align_up(off + (size_t)NN * 4, 256);
    unsigned short* slots = (unsigned short*)(ws + off); off = align_up(off + (size_t)NN * SLOTS * 2, 256);
    unsigned short* W1p = (unsigned short*)(ws + off); off = align_up(off + (size_t)HD * KP1 * 2, 256);
    unsigned short* W2p = (unsigned short*)(ws + off); off = align_up(off + (size_t)HD * KP2 * 2, 256);
    (void)ws_size;

    // weight cast (fragment-packed) + cursor zeroing
    k_castW<<<(HD * (KP1 + KP2) + 255) / 256, 256, 0, stream>>>(W1, W2, W1p, W2p, cursor);

    // merged: layer-1 GEMM || adjacency scatter (independent workloads)
    k_pre<<<GB1 + NSC, 256, 0, stream>>>(x, W1p, h1, asrc, adst, a_src1, a_dst1, NN,
                                         ei, cursor, slots);

    // Layer 1 aggregation
    k_gat<<<(NN + 3) / 4, 256, 0, stream>>>(h1, asrc, adst, cursor, slots, b1, o1);

    // Layer 2
    k_gemm2<<<GB1, 256, 0, stream>>>(o1, W2p, h1, asrc, adst, a_src2, a_dst2, NN);
    k_gat<<<(NN + 3) / 4, 256, 0, stream>>>(h1, asrc, adst, cursor, slots, b2, o1);

    // Pool + FC head
    k_poolfc<<<NG, 512, 0, stream>>>(o1, batch, fc1_w, fc1_b, fc2_w, fc2_b, out);
}